// Round 1
// baseline (456.601 us; speedup 1.0000x reference)
//
#include <hip/hip_runtime.h>

#define NG 128

// deg[dst] += 1 for every edge (self-loop +1 folded into dis_kernel)
__global__ void deg_kernel(const int* __restrict__ ei, int E, float* __restrict__ deg) {
  int e = blockIdx.x * blockDim.x + threadIdx.x;
  if (e < E) atomicAdd(&deg[ei[E + e]], 1.0f);
}

__global__ void dis_kernel(float* __restrict__ dis, int N) {
  int i = blockIdx.x * blockDim.x + threadIdx.x;
  if (i < N) dis[i] = rsqrtf(dis[i] + 1.0f);  // +1 = self loop; deg>0 always
}

// agg0[dst] += norm * x[src]  (4-dim aggregation, layer-1 commuted)
__global__ void agg0_kernel(const int* __restrict__ ei, int E,
                            const float* __restrict__ x,
                            const float* __restrict__ dis,
                            float* __restrict__ agg0) {
  int e = blockIdx.x * blockDim.x + threadIdx.x;
  if (e >= E) return;
  int s = ei[e], d = ei[E + e];
  float nrm = dis[s] * dis[d];
  float4 xv = ((const float4*)x)[s];
  atomicAdd(&agg0[d * 4 + 0], nrm * xv.x);
  atomicAdd(&agg0[d * 4 + 1], nrm * xv.y);
  atomicAdd(&agg0[d * 4 + 2], nrm * xv.z);
  atomicAdd(&agg0[d * 4 + 3], nrm * xv.w);
}

// h1 = relu((agg0 + dis^2 * x) @ W1 + b1); thread = (node, feature)
__global__ void h1_kernel(const float* __restrict__ agg0, const float* __restrict__ x,
                          const float* __restrict__ dis, const float* __restrict__ W1,
                          const float* __restrict__ b1, float* __restrict__ h1, int N) {
  int t = blockIdx.x * blockDim.x + threadIdx.x;
  int n = t >> 6, j = t & 63;
  if (n >= N) return;
  float di = dis[n], sl = di * di;
  float4 a = ((const float4*)agg0)[n];
  float4 xv = ((const float4*)x)[n];
  float v0 = a.x + sl * xv.x, v1 = a.y + sl * xv.y;
  float v2 = a.z + sl * xv.z, v3 = a.w + sl * xv.w;
  float acc = b1[j] + v0 * W1[j] + v1 * W1[64 + j] + v2 * W1[128 + j] + v3 * W1[192 + j];
  h1[(long)n * 64 + j] = fmaxf(acc, 0.0f);
}

// agg1[dst] += norm * h1[src]; one wave per edge, lane = feature
__global__ void agg1_kernel(const int* __restrict__ ei, int E,
                            const float* __restrict__ h1,
                            const float* __restrict__ dis,
                            float* __restrict__ agg1) {
  long t = (long)blockIdx.x * blockDim.x + threadIdx.x;
  int e = (int)(t >> 6), j = (int)(t & 63);
  if (e >= E) return;
  int s = ei[e], d = ei[E + e];
  float nrm = dis[s] * dis[d];
  atomicAdd(&agg1[(long)d * 64 + j], nrm * h1[(long)s * 64 + j]);
}

// h2 = relu((agg1 + dis^2*h1) @ W2 + b2) fused with pooled sum accumulation
__global__ void h2pool_kernel(const float* __restrict__ agg1, const float* __restrict__ h1,
                              const float* __restrict__ dis, const float* __restrict__ W2,
                              const float* __restrict__ b2, const int* __restrict__ batch,
                              float* __restrict__ gsum, int N) {
  int t = blockIdx.x * blockDim.x + threadIdx.x;
  int n = t >> 6, j = t & 63;
  if (n >= N) return;
  float di = dis[n], sl = di * di;
  float v = agg1[(long)n * 64 + j] + sl * h1[(long)n * 64 + j];
  float acc = b2[j];
#pragma unroll
  for (int k = 0; k < 64; ++k) {
    acc += __shfl(v, k, 64) * W2[k * 64 + j];
  }
  acc = fmaxf(acc, 0.0f);
  int g = batch[n];
  atomicAdd(&gsum[g * 64 + j], acc);
}

// batch is sorted: per-graph node counts from segment boundaries (no contention)
__global__ void bounds_kernel(const int* __restrict__ batch, int* __restrict__ gstart,
                              int* __restrict__ gend, int N) {
  int n = blockIdx.x * blockDim.x + threadIdx.x;
  if (n >= N) return;
  int b = batch[n];
  if (n == 0 || batch[n - 1] != b) gstart[b] = n;
  if (n == N - 1 || batch[n + 1] != b) gend[b] = n + 1;
}

__global__ void out_kernel(const float* __restrict__ gsum, const int* __restrict__ gstart,
                           const int* __restrict__ gend, float* __restrict__ out) {
  int t = blockIdx.x * blockDim.x + threadIdx.x;
  if (t >= NG * 64) return;
  int g = t >> 6;
  float cnt = (float)(gend[g] - gstart[g]);
  out[t] = gsum[t] / fmaxf(cnt, 1.0f);
}

extern "C" void kernel_launch(void* const* d_in, const int* in_sizes, int n_in,
                              void* d_out, int out_size, void* d_ws, size_t ws_size,
                              hipStream_t stream) {
  const float* x = (const float*)d_in[0];
  const int* ei = (const int*)d_in[1];     // [2, E] row-major: src row then dst row
  const int* batch = (const int*)d_in[2];  // sorted graph ids
  // d_in[3] = num_graphs scalar (= NG = 128, fixed problem size)
  const float* W1 = (const float*)d_in[4];
  const float* b1 = (const float*)d_in[5];
  const float* W2 = (const float*)d_in[6];
  const float* b2 = (const float*)d_in[7];

  const int N = in_sizes[0] / 4;
  const int E = in_sizes[1] / 2;

  // workspace layout (floats): [dis N][agg0 4N][agg1 64N][gsum 64*NG][gstart NG][gend NG][h1 64N]
  float* ws = (float*)d_ws;
  float* dis = ws;
  float* agg0 = dis + N;
  float* agg1 = agg0 + (long)4 * N;
  float* gsum = agg1 + (long)64 * N;
  int* gstart = (int*)(gsum + 64 * NG);
  int* gend = gstart + NG;
  float* h1 = (float*)(gend + NG);

  // zero everything that is accumulated into (h1 is fully overwritten, skip it)
  size_t zero_bytes = ((size_t)N * 69 + 64 * NG + 2 * NG) * sizeof(float);
  hipMemsetAsync(d_ws, 0, zero_bytes, stream);

  const int B = 256;
  deg_kernel<<<(E + B - 1) / B, B, 0, stream>>>(ei, E, dis);
  dis_kernel<<<(N + B - 1) / B, B, 0, stream>>>(dis, N);
  agg0_kernel<<<(E + B - 1) / B, B, 0, stream>>>(ei, E, x, dis, agg0);
  h1_kernel<<<((long)N * 64 + B - 1) / B, B, 0, stream>>>(agg0, x, dis, W1, b1, h1, N);
  agg1_kernel<<<((long)E * 64 + B - 1) / B, B, 0, stream>>>(ei, E, h1, dis, agg1);
  h2pool_kernel<<<((long)N * 64 + B - 1) / B, B, 0, stream>>>(agg1, h1, dis, W2, b2, batch, gsum, N);
  bounds_kernel<<<(N + B - 1) / B, B, 0, stream>>>(batch, gstart, gend, N);
  out_kernel<<<(NG * 64 + B - 1) / B, B, 0, stream>>>(gsum, gstart, gend, (float*)d_out);
}

// Round 2
// 330.998 us; speedup vs baseline: 1.3795x; 1.3795x over previous
//
#include <hip/hip_runtime.h>

#define NG 128

// ---- CSR build ----------------------------------------------------------

// in-degree histogram (int)
__global__ void cnt_kernel(const int* __restrict__ ei, int E, int* __restrict__ cnt) {
  int e = blockIdx.x * blockDim.x + threadIdx.x;
  if (e < E) atomicAdd(&cnt[ei[E + e]], 1);
}

// single-block exclusive scan of cnt[N] -> rowptr[N] and cursor[N]
__global__ void scan_kernel(const int* __restrict__ cnt, int* __restrict__ rowptr,
                            int* __restrict__ cursor, int N) {
  __shared__ int ssum[16];
  const int tid = threadIdx.x;           // 1024 threads
  const int chunk = (N + 1023) / 1024;
  const int begin = tid * chunk;
  const int end = (begin + chunk < N) ? (begin + chunk) : N;
  int local = 0;
  for (int i = begin; i < end; ++i) local += cnt[i];
  const int lane = tid & 63, wid = tid >> 6;
  int v = local;
  for (int off = 1; off < 64; off <<= 1) {
    int u = __shfl_up(v, off, 64);
    if (lane >= off) v += u;
  }
  if (lane == 63) ssum[wid] = v;
  __syncthreads();
  if (wid == 0) {
    int w = (lane < 16) ? ssum[lane] : 0;
    for (int off = 1; off < 16; off <<= 1) {
      int u = __shfl_up(w, off, 64);
      if (lane >= off) w += u;
    }
    if (lane < 16) ssum[lane] = w;
  }
  __syncthreads();
  int base = (wid > 0 ? ssum[wid - 1] : 0) + v - local;  // exclusive prefix of this thread
  int run = base;
  for (int i = begin; i < end; ++i) {
    rowptr[i] = run;
    cursor[i] = run;
    run += cnt[i];
  }
}

// counting-sort scatter: bucket src ids by dst
__global__ void scatter_kernel(const int* __restrict__ ei, int E,
                               int* __restrict__ cursor, int* __restrict__ esrc) {
  int e = blockIdx.x * blockDim.x + threadIdx.x;
  if (e >= E) return;
  int s = ei[e], d = ei[E + e];
  int pos = atomicAdd(&cursor[d], 1);
  esrc[pos] = s;
}

__global__ void dis_kernel(const int* __restrict__ cnt, float* __restrict__ dis, int N) {
  int i = blockIdx.x * blockDim.x + threadIdx.x;
  if (i < N) dis[i] = rsqrtf((float)cnt[i] + 1.0f);  // +1 self loop
}

// ---- layer 1 (aggregate in 4-dim, commuted) -----------------------------

// agg0[d] = dis[d] * ( sum_s dis[s]*x[s] + dis[d]*x[d] )
__global__ void agg0_kernel(const int* __restrict__ rowptr, const int* __restrict__ cnt,
                            const int* __restrict__ esrc, const float* __restrict__ x,
                            const float* __restrict__ dis, float* __restrict__ agg0, int N) {
  int d = blockIdx.x * blockDim.x + threadIdx.x;
  if (d >= N) return;
  float di = dis[d];
  float4 xv = ((const float4*)x)[d];
  float a0 = di * xv.x, a1 = di * xv.y, a2 = di * xv.z, a3 = di * xv.w;
  int p = rowptr[d], p1 = p + cnt[d];
  for (; p < p1; ++p) {
    int s = esrc[p];
    float w = dis[s];
    float4 v = ((const float4*)x)[s];
    a0 += w * v.x; a1 += w * v.y; a2 += w * v.z; a3 += w * v.w;
  }
  ((float4*)agg0)[d] = make_float4(di * a0, di * a1, di * a2, di * a3);
}

// h1 = relu(agg0 @ W1 + b1); thread = (node, feature)
__global__ void h1_kernel(const float* __restrict__ agg0, const float* __restrict__ W1,
                          const float* __restrict__ b1, float* __restrict__ h1, int N) {
  int t = blockIdx.x * blockDim.x + threadIdx.x;
  int n = t >> 6, j = t & 63;
  if (n >= N) return;
  float4 a = ((const float4*)agg0)[n];
  float acc = b1[j] + a.x * W1[j] + a.y * W1[64 + j] + a.z * W1[128 + j] + a.w * W1[192 + j];
  h1[n * 64 + j] = fmaxf(acc, 0.0f);
}

// ---- layer 2 fused: gather + matmul + relu + pool -----------------------

// wave per node d, lane j: v = dis[d]*( sum_s dis[s]*h1[s][j] + dis[d]*h1[d][j] )
// h2[j] = relu(b2[j] + sum_k v[k]*W2[k][j]);  gsum[batch[d]] += h2
__global__ void l2_kernel(const int* __restrict__ rowptr, const int* __restrict__ cnt,
                          const int* __restrict__ esrc, const float* __restrict__ h1,
                          const float* __restrict__ dis, const float* __restrict__ W2,
                          const float* __restrict__ b2, const int* __restrict__ batch,
                          float* __restrict__ gsum, int N) {
  long t = (long)blockIdx.x * blockDim.x + threadIdx.x;
  int d = (int)(t >> 6), j = (int)(t & 63);
  if (d >= N) return;
  float di = dis[d];
  float acc = di * h1[d * 64 + j];  // self loop (before final *di)
  int p0 = rowptr[d], n = cnt[d];
  for (int base = 0; base < n; base += 64) {
    int rem = n - base; if (rem > 64) rem = 64;
    int s_l = 0; float w_l = 0.0f;
    if (j < rem) { s_l = esrc[p0 + base + j]; w_l = dis[s_l]; }
    for (int k = 0; k < rem; ++k) {
      int s = __shfl(s_l, k, 64);
      float w = __shfl(w_l, k, 64);
      acc += w * h1[s * 64 + j];
    }
  }
  float v = di * acc;
  float o = b2[j];
#pragma unroll
  for (int k = 0; k < 64; ++k) o += __shfl(v, k, 64) * W2[k * 64 + j];
  o = fmaxf(o, 0.0f);
  atomicAdd(&gsum[batch[d] * 64 + j], o);
}

// ---- pooling normalization ----------------------------------------------

__global__ void bounds_kernel(const int* __restrict__ batch, int* __restrict__ gstart,
                              int* __restrict__ gend, int N) {
  int n = blockIdx.x * blockDim.x + threadIdx.x;
  if (n >= N) return;
  int b = batch[n];
  if (n == 0 || batch[n - 1] != b) gstart[b] = n;
  if (n == N - 1 || batch[n + 1] != b) gend[b] = n + 1;
}

__global__ void out_kernel(const float* __restrict__ gsum, const int* __restrict__ gstart,
                           const int* __restrict__ gend, float* __restrict__ out) {
  int t = blockIdx.x * blockDim.x + threadIdx.x;
  if (t >= NG * 64) return;
  int g = t >> 6;
  float cnt = (float)(gend[g] - gstart[g]);
  out[t] = gsum[t] / fmaxf(cnt, 1.0f);
}

// ---- launch --------------------------------------------------------------

extern "C" void kernel_launch(void* const* d_in, const int* in_sizes, int n_in,
                              void* d_out, int out_size, void* d_ws, size_t ws_size,
                              hipStream_t stream) {
  const float* x = (const float*)d_in[0];
  const int* ei = (const int*)d_in[1];     // [2,E]: src row then dst row
  const int* batch = (const int*)d_in[2];  // sorted graph ids
  const float* W1 = (const float*)d_in[4];
  const float* b1 = (const float*)d_in[5];
  const float* W2 = (const float*)d_in[6];
  const float* b2 = (const float*)d_in[7];

  const int N = in_sizes[0] / 4;
  const int E = in_sizes[1] / 2;

  // ws layout (ints/floats, 4B each):
  // [cnt N][gsum 64*NG][gstart NG][gend NG] <- zeroed each call
  // [rowptr N][cursor N][esrc E][dis N][agg0 4N][h1 64N]
  int* cnt = (int*)d_ws;
  float* gsum = (float*)(cnt + N);
  int* gstart = (int*)(gsum + 64 * NG);
  int* gend = gstart + NG;
  int* rowptr = gend + NG;
  int* cursor = rowptr + N;
  int* esrc = cursor + N;
  float* dis = (float*)(esrc + E);
  float* agg0 = dis + N;
  float* h1 = agg0 + (long)4 * N;

  size_t zero_bytes = ((size_t)N + 64 * NG + 2 * NG) * 4;
  hipMemsetAsync(d_ws, 0, zero_bytes, stream);

  const int B = 256;
  cnt_kernel<<<(E + B - 1) / B, B, 0, stream>>>(ei, E, cnt);
  scan_kernel<<<1, 1024, 0, stream>>>(cnt, rowptr, cursor, N);
  scatter_kernel<<<(E + B - 1) / B, B, 0, stream>>>(ei, E, cursor, esrc);
  dis_kernel<<<(N + B - 1) / B, B, 0, stream>>>(cnt, dis, N);
  agg0_kernel<<<(N + B - 1) / B, B, 0, stream>>>(rowptr, cnt, esrc, x, dis, agg0, N);
  h1_kernel<<<((long)N * 64 + B - 1) / B, B, 0, stream>>>(agg0, W1, b1, h1, N);
  l2_kernel<<<((long)N * 64 + B - 1) / B, B, 0, stream>>>(rowptr, cnt, esrc, h1, dis, W2, b2,
                                                          batch, gsum, N);
  bounds_kernel<<<(N + B - 1) / B, B, 0, stream>>>(batch, gstart, gend, N);
  out_kernel<<<(NG * 64 + B - 1) / B, B, 0, stream>>>(gsum, gstart, gend, (float*)d_out);
}

// Round 3
// 234.362 us; speedup vs baseline: 1.9483x; 1.4123x over previous
//
#include <hip/hip_runtime.h>

#define NG 128

__device__ __forceinline__ int wave_iscan(int v, int lane) {
#pragma unroll
  for (int off = 1; off < 64; off <<= 1) {
    int u = __shfl_up(v, off, 64);
    if (lane >= off) v += u;
  }
  return v;
}

// ---- CSR build ----------------------------------------------------------

// in-degree histogram (int)
__global__ void cnt_kernel(const int* __restrict__ ei, int E, int* __restrict__ cnt) {
  int e = blockIdx.x * blockDim.x + threadIdx.x;
  if (e < E) atomicAdd(&cnt[ei[E + e]], 1);
}

// phase 1: per-block sums of cnt (256 elems/block)
__global__ void bsum_kernel(const int* __restrict__ cnt, int* __restrict__ bsum, int N) {
  __shared__ int wsum[4];
  int tid = threadIdx.x, lane = tid & 63, wid = tid >> 6;
  int i = blockIdx.x * 256 + tid;
  int v = (i < N) ? cnt[i] : 0;
  int inc = wave_iscan(v, lane);
  if (lane == 63) wsum[wid] = inc;
  __syncthreads();
  if (tid == 0) bsum[blockIdx.x] = wsum[0] + wsum[1] + wsum[2] + wsum[3];
}

// phase 2: exclusive scan of bsum[nb] in one 1024-thread block (nb <= 1024)
__global__ void bscan_kernel(int* __restrict__ bsum, int nb) {
  __shared__ int wsum[16];
  int tid = threadIdx.x, lane = tid & 63, wid = tid >> 6;
  int v = (tid < nb) ? bsum[tid] : 0;
  int inc = wave_iscan(v, lane);
  if (lane == 63) wsum[wid] = inc;
  __syncthreads();
  if (tid == 0) {
    int a = 0;
#pragma unroll
    for (int w = 0; w < 16; ++w) { int t = wsum[w]; wsum[w] = a; a += t; }
  }
  __syncthreads();
  if (tid < nb) bsum[tid] = inc - v + wsum[wid];  // exclusive
}

// phase 3: rowptr[i] = exclusive_scan(cnt)[i]; cursor = copy
__global__ void rowptr_kernel(const int* __restrict__ cnt, const int* __restrict__ bsum,
                              int* __restrict__ rowptr, int* __restrict__ cursor, int N) {
  __shared__ int wsum[4];
  int tid = threadIdx.x, lane = tid & 63, wid = tid >> 6;
  int i = blockIdx.x * 256 + tid;
  int v = (i < N) ? cnt[i] : 0;
  int inc = wave_iscan(v, lane);
  if (lane == 63) wsum[wid] = inc;
  __syncthreads();
  if (tid == 0) {
    int a = bsum[blockIdx.x];
#pragma unroll
    for (int w = 0; w < 4; ++w) { int t = wsum[w]; wsum[w] = a; a += t; }
  }
  __syncthreads();
  if (i < N) {
    int exc = inc - v + wsum[wid];
    rowptr[i] = exc;
    cursor[i] = exc;
  }
}

// counting-sort scatter: bucket src ids by dst
__global__ void scatter_kernel(const int* __restrict__ ei, int E,
                               int* __restrict__ cursor, int* __restrict__ esrc) {
  int e = blockIdx.x * blockDim.x + threadIdx.x;
  if (e >= E) return;
  int s = ei[e], d = ei[E + e];
  int pos = atomicAdd(&cursor[d], 1);
  esrc[pos] = s;
}

__global__ void dis_kernel(const int* __restrict__ cnt, float* __restrict__ dis, int N) {
  int i = blockIdx.x * blockDim.x + threadIdx.x;
  if (i < N) dis[i] = rsqrtf((float)cnt[i] + 1.0f);  // +1 self loop
}

// ---- layer 1 (aggregate in 4-dim, commuted) -----------------------------

// agg0[d] = dis[d] * ( sum_s dis[s]*x[s] + dis[d]*x[d] )
__global__ void agg0_kernel(const int* __restrict__ rowptr, const int* __restrict__ cnt,
                            const int* __restrict__ esrc, const float* __restrict__ x,
                            const float* __restrict__ dis, float* __restrict__ agg0, int N) {
  int d = blockIdx.x * blockDim.x + threadIdx.x;
  if (d >= N) return;
  float di = dis[d];
  float4 xv = ((const float4*)x)[d];
  float a0 = di * xv.x, a1 = di * xv.y, a2 = di * xv.z, a3 = di * xv.w;
  int p = rowptr[d], p1 = p + cnt[d];
  for (; p < p1; ++p) {
    int s = esrc[p];
    float w = dis[s];
    float4 v = ((const float4*)x)[s];
    a0 += w * v.x; a1 += w * v.y; a2 += w * v.z; a3 += w * v.w;
  }
  ((float4*)agg0)[d] = make_float4(di * a0, di * a1, di * a2, di * a3);
}

// h1 = relu(agg0 @ W1 + b1); thread = (node, feature)
__global__ void h1_kernel(const float* __restrict__ agg0, const float* __restrict__ W1,
                          const float* __restrict__ b1, float* __restrict__ h1, int N) {
  int t = blockIdx.x * blockDim.x + threadIdx.x;
  int n = t >> 6, j = t & 63;
  if (n >= N) return;
  float4 a = ((const float4*)agg0)[n];
  float acc = b1[j] + a.x * W1[j] + a.y * W1[64 + j] + a.z * W1[128 + j] + a.w * W1[192 + j];
  h1[n * 64 + j] = fmaxf(acc, 0.0f);
}

// ---- layer 2 fused: gather + matmul + relu + pool -----------------------

// wave per node d, lane j: v = dis[d]*( sum_s dis[s]*h1[s][j] + dis[d]*h1[d][j] )
// h2[j] = relu(b2[j] + sum_k v[k]*W2[k][j]);  gsum[batch[d]] += h2
__global__ void l2_kernel(const int* __restrict__ rowptr, const int* __restrict__ cnt,
                          const int* __restrict__ esrc, const float* __restrict__ h1,
                          const float* __restrict__ dis, const float* __restrict__ W2,
                          const float* __restrict__ b2, const int* __restrict__ batch,
                          float* __restrict__ gsum, int N) {
  long t = (long)blockIdx.x * blockDim.x + threadIdx.x;
  int d = (int)(t >> 6), j = (int)(t & 63);
  if (d >= N) return;
  float di = dis[d];
  float acc = di * h1[d * 64 + j];  // self loop (before final *di)
  int p0 = rowptr[d], n = cnt[d];
  for (int base = 0; base < n; base += 64) {
    int rem = n - base; if (rem > 64) rem = 64;
    int s_l = 0; float w_l = 0.0f;
    if (j < rem) { s_l = esrc[p0 + base + j]; w_l = dis[s_l]; }
    for (int k = 0; k < rem; ++k) {
      int s = __shfl(s_l, k, 64);
      float w = __shfl(w_l, k, 64);
      acc += w * h1[s * 64 + j];
    }
  }
  float v = di * acc;
  float o = b2[j];
#pragma unroll
  for (int k = 0; k < 64; ++k) o += __shfl(v, k, 64) * W2[k * 64 + j];
  o = fmaxf(o, 0.0f);
  atomicAdd(&gsum[batch[d] * 64 + j], o);
}

// ---- pooling normalization ----------------------------------------------

__global__ void bounds_kernel(const int* __restrict__ batch, int* __restrict__ gstart,
                              int* __restrict__ gend, int N) {
  int n = blockIdx.x * blockDim.x + threadIdx.x;
  if (n >= N) return;
  int b = batch[n];
  if (n == 0 || batch[n - 1] != b) gstart[b] = n;
  if (n == N - 1 || batch[n + 1] != b) gend[b] = n + 1;
}

__global__ void out_kernel(const float* __restrict__ gsum, const int* __restrict__ gstart,
                           const int* __restrict__ gend, float* __restrict__ out) {
  int t = blockIdx.x * blockDim.x + threadIdx.x;
  if (t >= NG * 64) return;
  int g = t >> 6;
  float cnt = (float)(gend[g] - gstart[g]);
  out[t] = gsum[t] / fmaxf(cnt, 1.0f);
}

// ---- launch --------------------------------------------------------------

extern "C" void kernel_launch(void* const* d_in, const int* in_sizes, int n_in,
                              void* d_out, int out_size, void* d_ws, size_t ws_size,
                              hipStream_t stream) {
  const float* x = (const float*)d_in[0];
  const int* ei = (const int*)d_in[1];     // [2,E]: src row then dst row
  const int* batch = (const int*)d_in[2];  // sorted graph ids
  const float* W1 = (const float*)d_in[4];
  const float* b1 = (const float*)d_in[5];
  const float* W2 = (const float*)d_in[6];
  const float* b2 = (const float*)d_in[7];

  const int N = in_sizes[0] / 4;
  const int E = in_sizes[1] / 2;
  const int NB = (N + 255) / 256;  // blocks for scan phases (<= 1024)

  // ws layout (4B units):
  // [cnt N][gsum 64*NG][gstart NG][gend NG] <- zeroed each call
  // [rowptr N][cursor N][esrc E][dis N][agg0 4N][h1 64N][bsum NB]
  int* cnt = (int*)d_ws;
  float* gsum = (float*)(cnt + N);
  int* gstart = (int*)(gsum + 64 * NG);
  int* gend = gstart + NG;
  int* rowptr = gend + NG;
  int* cursor = rowptr + N;
  int* esrc = cursor + N;
  float* dis = (float*)(esrc + E);
  float* agg0 = dis + N;
  float* h1 = agg0 + (long)4 * N;
  int* bsum = (int*)(h1 + (long)64 * N);

  size_t zero_bytes = ((size_t)N + 64 * NG + 2 * NG) * 4;
  hipMemsetAsync(d_ws, 0, zero_bytes, stream);

  const int B = 256;
  cnt_kernel<<<(E + B - 1) / B, B, 0, stream>>>(ei, E, cnt);
  bsum_kernel<<<NB, 256, 0, stream>>>(cnt, bsum, N);
  bscan_kernel<<<1, 1024, 0, stream>>>(bsum, NB);
  rowptr_kernel<<<NB, 256, 0, stream>>>(cnt, bsum, rowptr, cursor, N);
  scatter_kernel<<<(E + B - 1) / B, B, 0, stream>>>(ei, E, cursor, esrc);
  dis_kernel<<<(N + B - 1) / B, B, 0, stream>>>(cnt, dis, N);
  agg0_kernel<<<(N + B - 1) / B, B, 0, stream>>>(rowptr, cnt, esrc, x, dis, agg0, N);
  h1_kernel<<<((long)N * 64 + B - 1) / B, B, 0, stream>>>(agg0, W1, b1, h1, N);
  l2_kernel<<<((long)N * 64 + B - 1) / B, B, 0, stream>>>(rowptr, cnt, esrc, h1, dis, W2, b2,
                                                          batch, gsum, N);
  bounds_kernel<<<(N + B - 1) / B, B, 0, stream>>>(batch, gstart, gend, N);
  out_kernel<<<(NG * 64 + B - 1) / B, B, 0, stream>>>(gsum, gstart, gend, (float*)d_out);
}

// Round 4
// 206.723 us; speedup vs baseline: 2.2088x; 1.1337x over previous
//
#include <hip/hip_runtime.h>

#define NG 128

__device__ __forceinline__ int wave_iscan(int v, int lane) {
#pragma unroll
  for (int off = 1; off < 64; off <<= 1) {
    int u = __shfl_up(v, off, 64);
    if (lane >= off) v += u;
  }
  return v;
}

// ---- CSR build ----------------------------------------------------------

__global__ void cnt_kernel(const int* __restrict__ ei, int E, int* __restrict__ cnt) {
  int e = blockIdx.x * blockDim.x + threadIdx.x;
  if (e < E) atomicAdd(&cnt[ei[E + e]], 1);
}

// phase 1: per-block sums of cnt (256 elems/block)
__global__ void bsum_kernel(const int* __restrict__ cnt, int* __restrict__ bsum, int N) {
  __shared__ int wsum[4];
  int tid = threadIdx.x, lane = tid & 63, wid = tid >> 6;
  int i = blockIdx.x * 256 + tid;
  int v = (i < N) ? cnt[i] : 0;
  int inc = wave_iscan(v, lane);
  if (lane == 63) wsum[wid] = inc;
  __syncthreads();
  if (tid == 0) bsum[blockIdx.x] = wsum[0] + wsum[1] + wsum[2] + wsum[3];
}

// phase 2: exclusive scan of bsum[nb] (nb <= 1024)
__global__ void bscan_kernel(int* __restrict__ bsum, int nb) {
  __shared__ int wsum[16];
  int tid = threadIdx.x, lane = tid & 63, wid = tid >> 6;
  int v = (tid < nb) ? bsum[tid] : 0;
  int inc = wave_iscan(v, lane);
  if (lane == 63) wsum[wid] = inc;
  __syncthreads();
  if (tid == 0) {
    int a = 0;
#pragma unroll
    for (int w = 0; w < 16; ++w) { int t = wsum[w]; wsum[w] = a; a += t; }
  }
  __syncthreads();
  if (tid < nb) bsum[tid] = inc - v + wsum[wid];
}

// phase 3: rowptr = exclusive scan; cursor = copy; dis = rsqrt(deg+1)
__global__ void rowptr_kernel(const int* __restrict__ cnt, const int* __restrict__ bsum,
                              int* __restrict__ rowptr, int* __restrict__ cursor,
                              float* __restrict__ dis, int N) {
  __shared__ int wsum[4];
  int tid = threadIdx.x, lane = tid & 63, wid = tid >> 6;
  int i = blockIdx.x * 256 + tid;
  int v = (i < N) ? cnt[i] : 0;
  int inc = wave_iscan(v, lane);
  if (lane == 63) wsum[wid] = inc;
  __syncthreads();
  if (tid == 0) {
    int a = bsum[blockIdx.x];
#pragma unroll
    for (int w = 0; w < 4; ++w) { int t = wsum[w]; wsum[w] = a; a += t; }
  }
  __syncthreads();
  if (i < N) {
    int exc = inc - v + wsum[wid];
    rowptr[i] = exc;
    cursor[i] = exc;
    dis[i] = rsqrtf((float)v + 1.0f);  // +1 self loop
  }
}

// counting-sort scatter: epk[pos] = (src, dis[src]) bucketed by dst
__global__ void scatter_kernel(const int* __restrict__ ei, int E,
                               int* __restrict__ cursor, const float* __restrict__ dis,
                               int2* __restrict__ epk) {
  int e = blockIdx.x * blockDim.x + threadIdx.x;
  if (e >= E) return;
  int s = ei[e], d = ei[E + e];
  int pos = atomicAdd(&cursor[d], 1);
  epk[pos] = make_int2(s, __float_as_int(dis[s]));
}

// ---- layer 1 (aggregate in 4-dim, commuted) -----------------------------

// agg0[d] = dis[d] * ( sum_s dis[s]*x[s] + dis[d]*x[d] ); unroll-4 for MLP
__global__ void agg0_kernel(const int* __restrict__ rowptr, const int* __restrict__ cnt,
                            const int2* __restrict__ epk, const float* __restrict__ x,
                            const float* __restrict__ dis, float* __restrict__ agg0, int N) {
  int d = blockIdx.x * blockDim.x + threadIdx.x;
  if (d >= N) return;
  float di = dis[d];
  float4 xv = ((const float4*)x)[d];
  float a0 = di * xv.x, a1 = di * xv.y, a2 = di * xv.z, a3 = di * xv.w;
  int p = rowptr[d], n = cnt[d];
  int k = 0;
  for (; k + 4 <= n; k += 4) {
    int2 e0 = epk[p + k], e1 = epk[p + k + 1], e2 = epk[p + k + 2], e3 = epk[p + k + 3];
    float4 v0 = ((const float4*)x)[e0.x];
    float4 v1 = ((const float4*)x)[e1.x];
    float4 v2 = ((const float4*)x)[e2.x];
    float4 v3 = ((const float4*)x)[e3.x];
    float w0 = __int_as_float(e0.y), w1 = __int_as_float(e1.y);
    float w2 = __int_as_float(e2.y), w3 = __int_as_float(e3.y);
    a0 += w0 * v0.x + w1 * v1.x + w2 * v2.x + w3 * v3.x;
    a1 += w0 * v0.y + w1 * v1.y + w2 * v2.y + w3 * v3.y;
    a2 += w0 * v0.z + w1 * v1.z + w2 * v2.z + w3 * v3.z;
    a3 += w0 * v0.w + w1 * v1.w + w2 * v2.w + w3 * v3.w;
  }
  for (; k < n; ++k) {
    int2 e = epk[p + k];
    float w = __int_as_float(e.y);
    float4 v = ((const float4*)x)[e.x];
    a0 += w * v.x; a1 += w * v.y; a2 += w * v.z; a3 += w * v.w;
  }
  ((float4*)agg0)[d] = make_float4(di * a0, di * a1, di * a2, di * a3);
}

// h1 = relu(agg0 @ W1 + b1); thread = (node, feature)
__global__ void h1_kernel(const float* __restrict__ agg0, const float* __restrict__ W1,
                          const float* __restrict__ b1, float* __restrict__ h1, int N) {
  int t = blockIdx.x * blockDim.x + threadIdx.x;
  int n = t >> 6, j = t & 63;
  if (n >= N) return;
  float4 a = ((const float4*)agg0)[n];
  float acc = b1[j] + a.x * W1[j] + a.y * W1[64 + j] + a.z * W1[128 + j] + a.w * W1[192 + j];
  h1[n * 64 + j] = fmaxf(acc, 0.0f);
}

// ---- layer 2 fused: gather + matmul + relu + pool -----------------------

__global__ void l2_kernel(const int* __restrict__ rowptr, const int* __restrict__ cnt,
                          const int2* __restrict__ epk, const float* __restrict__ h1,
                          const float* __restrict__ dis, const float* __restrict__ W2,
                          const float* __restrict__ b2, const int* __restrict__ batch,
                          float* __restrict__ gsum, int N) {
  long t = (long)blockIdx.x * blockDim.x + threadIdx.x;
  int d = (int)(t >> 6), j = (int)(t & 63);
  if (d >= N) return;
  float di = dis[d];
  float acc0 = di * h1[(long)d * 64 + j];  // self loop
  float acc1 = 0.f, acc2 = 0.f, acc3 = 0.f;
  int p0 = rowptr[d], n = cnt[d];
  for (int base = 0; base < n; base += 64) {
    int rem = n - base; if (rem > 64) rem = 64;
    int2 e = make_int2(0, 0);
    if (j < rem) e = epk[p0 + base + j];
    int s_l = e.x; float w_l = __int_as_float(e.y);
    int k = 0;
    for (; k + 4 <= rem; k += 4) {
      int s0 = __shfl(s_l, k, 64), s1 = __shfl(s_l, k + 1, 64);
      int s2 = __shfl(s_l, k + 2, 64), s3 = __shfl(s_l, k + 3, 64);
      float w0 = __shfl(w_l, k, 64), w1 = __shfl(w_l, k + 1, 64);
      float w2 = __shfl(w_l, k + 2, 64), w3 = __shfl(w_l, k + 3, 64);
      float v0 = h1[(long)s0 * 64 + j];
      float v1 = h1[(long)s1 * 64 + j];
      float v2 = h1[(long)s2 * 64 + j];
      float v3 = h1[(long)s3 * 64 + j];
      acc0 = fmaf(w0, v0, acc0);
      acc1 = fmaf(w1, v1, acc1);
      acc2 = fmaf(w2, v2, acc2);
      acc3 = fmaf(w3, v3, acc3);
    }
    for (; k < rem; ++k) {
      int s = __shfl(s_l, k, 64);
      float w = __shfl(w_l, k, 64);
      acc0 = fmaf(w, h1[(long)s * 64 + j], acc0);
    }
  }
  float v = di * ((acc0 + acc1) + (acc2 + acc3));
  float o = b2[j];
#pragma unroll
  for (int k = 0; k < 64; ++k) o = fmaf(__shfl(v, k, 64), W2[k * 64 + j], o);
  o = fmaxf(o, 0.0f);
  atomicAdd(&gsum[batch[d] * 64 + j], o);
}

// ---- pooling normalization ----------------------------------------------

__global__ void bounds_kernel(const int* __restrict__ batch, int* __restrict__ gstart,
                              int* __restrict__ gend, int N) {
  int n = blockIdx.x * blockDim.x + threadIdx.x;
  if (n >= N) return;
  int b = batch[n];
  if (n == 0 || batch[n - 1] != b) gstart[b] = n;
  if (n == N - 1 || batch[n + 1] != b) gend[b] = n + 1;
}

__global__ void out_kernel(const float* __restrict__ gsum, const int* __restrict__ gstart,
                           const int* __restrict__ gend, float* __restrict__ out) {
  int t = blockIdx.x * blockDim.x + threadIdx.x;
  if (t >= NG * 64) return;
  int g = t >> 6;
  float cnt = (float)(gend[g] - gstart[g]);
  out[t] = gsum[t] / fmaxf(cnt, 1.0f);
}

// ---- launch --------------------------------------------------------------

extern "C" void kernel_launch(void* const* d_in, const int* in_sizes, int n_in,
                              void* d_out, int out_size, void* d_ws, size_t ws_size,
                              hipStream_t stream) {
  const float* x = (const float*)d_in[0];
  const int* ei = (const int*)d_in[1];     // [2,E]: src row then dst row
  const int* batch = (const int*)d_in[2];  // sorted graph ids
  const float* W1 = (const float*)d_in[4];
  const float* b1 = (const float*)d_in[5];
  const float* W2 = (const float*)d_in[6];
  const float* b2 = (const float*)d_in[7];

  const int N = in_sizes[0] / 4;
  const int E = in_sizes[1] / 2;
  const int NB = (N + 255) / 256;  // <= 1024

  // ws layout (4B units):
  // [cnt N][gsum 64*NG][gstart NG][gend NG] <- zeroed each call
  // [rowptr N][cursor N][epk 2E][dis N][agg0 4N][h1 64N][bsum NB]
  int* cnt = (int*)d_ws;
  float* gsum = (float*)(cnt + N);
  int* gstart = (int*)(gsum + 64 * NG);
  int* gend = gstart + NG;
  int* rowptr = gend + NG;
  int* cursor = rowptr + N;
  int2* epk = (int2*)(cursor + N);  // 8B-aligned: preceding count is even
  float* dis = (float*)(epk + E);
  float* agg0 = dis + N;
  float* h1 = agg0 + (long)4 * N;
  int* bsum = (int*)(h1 + (long)64 * N);

  size_t zero_bytes = ((size_t)N + 64 * NG + 2 * NG) * 4;
  hipMemsetAsync(d_ws, 0, zero_bytes, stream);

  const int B = 256;
  cnt_kernel<<<(E + B - 1) / B, B, 0, stream>>>(ei, E, cnt);
  bsum_kernel<<<NB, 256, 0, stream>>>(cnt, bsum, N);
  bscan_kernel<<<1, 1024, 0, stream>>>(bsum, NB);
  rowptr_kernel<<<NB, 256, 0, stream>>>(cnt, bsum, rowptr, cursor, dis, N);
  scatter_kernel<<<(E + B - 1) / B, B, 0, stream>>>(ei, E, cursor, dis, epk);
  agg0_kernel<<<(N + B - 1) / B, B, 0, stream>>>(rowptr, cnt, epk, x, dis, agg0, N);
  h1_kernel<<<((long)N * 64 + B - 1) / B, B, 0, stream>>>(agg0, W1, b1, h1, N);
  l2_kernel<<<((long)N * 64 + B - 1) / B, B, 0, stream>>>(rowptr, cnt, epk, h1, dis, W2, b2,
                                                          batch, gsum, N);
  bounds_kernel<<<(N + B - 1) / B, B, 0, stream>>>(batch, gstart, gend, N);
  out_kernel<<<(NG * 64 + B - 1) / B, B, 0, stream>>>(gsum, gstart, gend, (float*)d_out);
}

// Round 5
// 186.382 us; speedup vs baseline: 2.4498x; 1.1091x over previous
//
#include <hip/hip_runtime.h>

#define NG 128

__device__ __forceinline__ int wave_iscan(int v, int lane) {
#pragma unroll
  for (int off = 1; off < 64; off <<= 1) {
    int u = __shfl_up(v, off, 64);
    if (lane >= off) v += u;
  }
  return v;
}

// ---- CSR build ----------------------------------------------------------

__global__ void cnt_kernel(const int* __restrict__ ei, int E, int* __restrict__ cnt) {
  int e = blockIdx.x * blockDim.x + threadIdx.x;
  if (e < E) atomicAdd(&cnt[ei[E + e]], 1);
}

// phase 1: per-block sums of cnt (256 elems/block)
__global__ void bsum_kernel(const int* __restrict__ cnt, int* __restrict__ bsum, int N) {
  __shared__ int wsum[4];
  int tid = threadIdx.x, lane = tid & 63, wid = tid >> 6;
  int i = blockIdx.x * 256 + tid;
  int v = (i < N) ? cnt[i] : 0;
  int inc = wave_iscan(v, lane);
  if (lane == 63) wsum[wid] = inc;
  __syncthreads();
  if (tid == 0) bsum[blockIdx.x] = wsum[0] + wsum[1] + wsum[2] + wsum[3];
}

// phase 2: exclusive scan of bsum[nb] (nb <= 1024)
__global__ void bscan_kernel(int* __restrict__ bsum, int nb) {
  __shared__ int wsum[16];
  int tid = threadIdx.x, lane = tid & 63, wid = tid >> 6;
  int v = (tid < nb) ? bsum[tid] : 0;
  int inc = wave_iscan(v, lane);
  if (lane == 63) wsum[wid] = inc;
  __syncthreads();
  if (tid == 0) {
    int a = 0;
#pragma unroll
    for (int w = 0; w < 16; ++w) { int t = wsum[w]; wsum[w] = a; a += t; }
  }
  __syncthreads();
  if (tid < nb) bsum[tid] = inc - v + wsum[wid];
}

// phase 3: rowptr = exclusive scan; cursor = copy; dis = rsqrt(deg+1)
__global__ void rowptr_kernel(const int* __restrict__ cnt, const int* __restrict__ bsum,
                              int* __restrict__ rowptr, int* __restrict__ cursor,
                              float* __restrict__ dis, int N) {
  __shared__ int wsum[4];
  int tid = threadIdx.x, lane = tid & 63, wid = tid >> 6;
  int i = blockIdx.x * 256 + tid;
  int v = (i < N) ? cnt[i] : 0;
  int inc = wave_iscan(v, lane);
  if (lane == 63) wsum[wid] = inc;
  __syncthreads();
  if (tid == 0) {
    int a = bsum[blockIdx.x];
#pragma unroll
    for (int w = 0; w < 4; ++w) { int t = wsum[w]; wsum[w] = a; a += t; }
  }
  __syncthreads();
  if (i < N) {
    int exc = inc - v + wsum[wid];
    rowptr[i] = exc;
    cursor[i] = exc;
    dis[i] = rsqrtf((float)v + 1.0f);  // +1 self loop
  }
}

// counting-sort scatter: epk[pos] = (src, dis[src]) bucketed by dst
__global__ void scatter_kernel(const int* __restrict__ ei, int E,
                               int* __restrict__ cursor, const float* __restrict__ dis,
                               int2* __restrict__ epk) {
  int e = blockIdx.x * blockDim.x + threadIdx.x;
  if (e >= E) return;
  int s = ei[e], d = ei[E + e];
  int pos = atomicAdd(&cursor[d], 1);
  epk[pos] = make_int2(s, __float_as_int(dis[s]));
}

// ---- layer 1 (aggregate in 4-dim, commuted) -----------------------------

// agg0[d] = dis[d] * ( sum_s dis[s]*x[s] + dis[d]*x[d] ); unroll-4 for MLP
__global__ void agg0_kernel(const int* __restrict__ rowptr, const int* __restrict__ cnt,
                            const int2* __restrict__ epk, const float* __restrict__ x,
                            const float* __restrict__ dis, float* __restrict__ agg0, int N) {
  int d = blockIdx.x * blockDim.x + threadIdx.x;
  if (d >= N) return;
  float di = dis[d];
  float4 xv = ((const float4*)x)[d];
  float a0 = di * xv.x, a1 = di * xv.y, a2 = di * xv.z, a3 = di * xv.w;
  int p = rowptr[d], n = cnt[d];
  int k = 0;
  for (; k + 4 <= n; k += 4) {
    int2 e0 = epk[p + k], e1 = epk[p + k + 1], e2 = epk[p + k + 2], e3 = epk[p + k + 3];
    float4 v0 = ((const float4*)x)[e0.x];
    float4 v1 = ((const float4*)x)[e1.x];
    float4 v2 = ((const float4*)x)[e2.x];
    float4 v3 = ((const float4*)x)[e3.x];
    float w0 = __int_as_float(e0.y), w1 = __int_as_float(e1.y);
    float w2 = __int_as_float(e2.y), w3 = __int_as_float(e3.y);
    a0 += w0 * v0.x + w1 * v1.x + w2 * v2.x + w3 * v3.x;
    a1 += w0 * v0.y + w1 * v1.y + w2 * v2.y + w3 * v3.y;
    a2 += w0 * v0.z + w1 * v1.z + w2 * v2.z + w3 * v3.z;
    a3 += w0 * v0.w + w1 * v1.w + w2 * v2.w + w3 * v3.w;
  }
  for (; k < n; ++k) {
    int2 e = epk[p + k];
    float w = __int_as_float(e.y);
    float4 v = ((const float4*)x)[e.x];
    a0 += w * v.x; a1 += w * v.y; a2 += w * v.z; a3 += w * v.w;
  }
  ((float4*)agg0)[d] = make_float4(di * a0, di * a1, di * a2, di * a3);
}

// h1 = relu(agg0 @ W1 + b1); thread = (node, feature)
__global__ void h1_kernel(const float* __restrict__ agg0, const float* __restrict__ W1,
                          const float* __restrict__ b1, float* __restrict__ h1, int N) {
  int t = blockIdx.x * blockDim.x + threadIdx.x;
  int n = t >> 6, j = t & 63;
  if (n >= N) return;
  float4 a = ((const float4*)agg0)[n];
  float acc = b1[j] + a.x * W1[j] + a.y * W1[64 + j] + a.z * W1[128 + j] + a.w * W1[192 + j];
  h1[n * 64 + j] = fmaxf(acc, 0.0f);
}

// ---- layer 2 fused: gather + matmul + relu + pool -----------------------
// Wave per node. d is wave-uniform (readfirstlane) -> epk reads are uniform
// broadcast/scalar loads, no shfl. Matmul broadcast via per-wave LDS slice.
__global__ void l2_kernel(const int* __restrict__ rowptr, const int* __restrict__ cnt,
                          const int2* __restrict__ epk, const float* __restrict__ h1,
                          const float* __restrict__ dis, const float* __restrict__ W2,
                          const float* __restrict__ b2, const int* __restrict__ batch,
                          float* __restrict__ gsum, int N) {
  __shared__ float vbuf[4][64];
  int tid = threadIdx.x;
  int j = tid & 63, wid = tid >> 6;
  int d = __builtin_amdgcn_readfirstlane(blockIdx.x * 4 + wid);
  if (d >= N) return;  // uniform exit
  float di = dis[d];
  float acc0 = di * h1[(long)d * 64 + j];  // self loop
  float acc1 = 0.f, acc2 = 0.f, acc3 = 0.f;
  int p = __builtin_amdgcn_readfirstlane(rowptr[d]);
  int n = __builtin_amdgcn_readfirstlane(cnt[d]);
  int k = 0;
  for (; k + 4 <= n; k += 4) {
    int2 e0 = epk[p + k], e1 = epk[p + k + 1], e2 = epk[p + k + 2], e3 = epk[p + k + 3];
    float v0 = h1[(long)e0.x * 64 + j];
    float v1 = h1[(long)e1.x * 64 + j];
    float v2 = h1[(long)e2.x * 64 + j];
    float v3 = h1[(long)e3.x * 64 + j];
    acc0 = fmaf(__int_as_float(e0.y), v0, acc0);
    acc1 = fmaf(__int_as_float(e1.y), v1, acc1);
    acc2 = fmaf(__int_as_float(e2.y), v2, acc2);
    acc3 = fmaf(__int_as_float(e3.y), v3, acc3);
  }
  for (; k < n; ++k) {
    int2 e = epk[p + k];
    acc0 = fmaf(__int_as_float(e.y), h1[(long)e.x * 64 + j], acc0);
  }
  float v = di * ((acc0 + acc1) + (acc2 + acc3));
  vbuf[wid][j] = v;  // intra-wave LDS: in-order per wave, no barrier needed
  float o = b2[j];
  const float4* vb4 = (const float4*)vbuf[wid];
#pragma unroll
  for (int kk = 0; kk < 16; ++kk) {
    float4 vv = vb4[kk];  // uniform address -> broadcast ds_read_b128
    o = fmaf(vv.x, W2[(kk * 4 + 0) * 64 + j], o);
    o = fmaf(vv.y, W2[(kk * 4 + 1) * 64 + j], o);
    o = fmaf(vv.z, W2[(kk * 4 + 2) * 64 + j], o);
    o = fmaf(vv.w, W2[(kk * 4 + 3) * 64 + j], o);
  }
  o = fmaxf(o, 0.0f);
  atomicAdd(&gsum[batch[d] * 64 + j], o);
}

// ---- pooling normalization ----------------------------------------------

__global__ void bounds_kernel(const int* __restrict__ batch, int* __restrict__ gstart,
                              int* __restrict__ gend, int N) {
  int n = blockIdx.x * blockDim.x + threadIdx.x;
  if (n >= N) return;
  int b = batch[n];
  if (n == 0 || batch[n - 1] != b) gstart[b] = n;
  if (n == N - 1 || batch[n + 1] != b) gend[b] = n + 1;
}

__global__ void out_kernel(const float* __restrict__ gsum, const int* __restrict__ gstart,
                           const int* __restrict__ gend, float* __restrict__ out) {
  int t = blockIdx.x * blockDim.x + threadIdx.x;
  if (t >= NG * 64) return;
  int g = t >> 6;
  float cnt = (float)(gend[g] - gstart[g]);
  out[t] = gsum[t] / fmaxf(cnt, 1.0f);
}

// ---- launch --------------------------------------------------------------

extern "C" void kernel_launch(void* const* d_in, const int* in_sizes, int n_in,
                              void* d_out, int out_size, void* d_ws, size_t ws_size,
                              hipStream_t stream) {
  const float* x = (const float*)d_in[0];
  const int* ei = (const int*)d_in[1];     // [2,E]: src row then dst row
  const int* batch = (const int*)d_in[2];  // sorted graph ids
  const float* W1 = (const float*)d_in[4];
  const float* b1 = (const float*)d_in[5];
  const float* W2 = (const float*)d_in[6];
  const float* b2 = (const float*)d_in[7];

  const int N = in_sizes[0] / 4;
  const int E = in_sizes[1] / 2;
  const int NB = (N + 255) / 256;  // <= 1024

  // ws layout (4B units):
  // [cnt N][gsum 64*NG][gstart NG][gend NG] <- zeroed each call
  // [rowptr N][cursor N][epk 2E][dis N][agg0 4N][h1 64N][bsum NB]
  int* cnt = (int*)d_ws;
  float* gsum = (float*)(cnt + N);
  int* gstart = (int*)(gsum + 64 * NG);
  int* gend = gstart + NG;
  int* rowptr = gend + NG;
  int* cursor = rowptr + N;
  int2* epk = (int2*)(cursor + N);  // 8B-aligned
  float* dis = (float*)(epk + E);
  float* agg0 = dis + N;
  float* h1 = agg0 + (long)4 * N;
  int* bsum = (int*)(h1 + (long)64 * N);

  size_t zero_bytes = ((size_t)N + 64 * NG + 2 * NG) * 4;
  hipMemsetAsync(d_ws, 0, zero_bytes, stream);

  const int B = 256;
  cnt_kernel<<<(E + B - 1) / B, B, 0, stream>>>(ei, E, cnt);
  bsum_kernel<<<NB, 256, 0, stream>>>(cnt, bsum, N);
  bscan_kernel<<<1, 1024, 0, stream>>>(bsum, NB);
  rowptr_kernel<<<NB, 256, 0, stream>>>(cnt, bsum, rowptr, cursor, dis, N);
  scatter_kernel<<<(E + B - 1) / B, B, 0, stream>>>(ei, E, cursor, dis, epk);
  agg0_kernel<<<(N + B - 1) / B, B, 0, stream>>>(rowptr, cnt, epk, x, dis, agg0, N);
  h1_kernel<<<((long)N * 64 + B - 1) / B, B, 0, stream>>>(agg0, W1, b1, h1, N);
  l2_kernel<<<(N + 3) / 4, 256, 0, stream>>>(rowptr, cnt, epk, h1, dis, W2, b2,
                                             batch, gsum, N);
  bounds_kernel<<<(N + B - 1) / B, B, 0, stream>>>(batch, gstart, gend, N);
  out_kernel<<<(NG * 64 + B - 1) / B, B, 0, stream>>>(gsum, gstart, gend, (float*)d_out);
}